// Round 1
// baseline (169.479 us; speedup 1.0000x reference)
//
#include <hip/hip_runtime.h>
#include <hip/hip_bf16.h>
#include <stdint.h>

// ECG beat tokenizer: X[196608, 64] = ecg_rows[196608, 128] @ W[64,128]^T + b
// plus beat_intervals[128*128] = 128.0f appended at out + 196608*64.
//
// Strategy: memory-bound skinny GEMM (151 MB traffic, ~24us floor @6.3TB/s).
// bf16 MFMA 16x16x32 so compute is negligible. A loaded global->reg directly
// in fragment layout (zero reuse), W held in registers per wave (full reuse).

#define BEAT_LEN   128
#define TOKEN_DIM  64
#define N_BATCH    128
#define N_BEATS    128
#define M_ROWS     196608          // 128*12*128 beat rows
#define RGROUPS    (M_ROWS / 16)   // 12288 row-groups of 16
#define NBLOCKS    1024
#define WPB        4               // waves per block (256 threads)
#define NWAVES     (NBLOCKS * WPB) // 4096 -> 3 row-groups per wave

typedef __attribute__((ext_vector_type(4))) float f32x4;
typedef __attribute__((ext_vector_type(8))) short bf16x8;

union ABFrag { bf16x8 v; uint32_t u[4]; };

// pack two fp32 into one dword of 2x bf16 (round-half-up; error << threshold)
__device__ __forceinline__ uint32_t pkbf16(float a, float b) {
    uint32_t ua = __float_as_uint(a);
    uint32_t ub = __float_as_uint(b);
    return ((ua + 0x8000u) >> 16) | ((ub + 0x8000u) & 0xffff0000u);
}

__global__ __launch_bounds__(256) void ECGTokenizer_53420803228140_kernel(
    const float* __restrict__ ecg, const float* __restrict__ W,
    const float* __restrict__ b, float* __restrict__ out)
{
    const int lane = threadIdx.x & 63;
    const int wid  = threadIdx.x >> 6;
    const int l16  = lane & 15;   // A row / B col / D col within tile
    const int lg   = lane >> 4;   // k-chunk group (0..3)

    // ---- W fragments, held in registers for the whole kernel ----
    // B[k][col] = W[col][k]; lane holds col=16c+l16, k = 32s + 8*lg + e (e=0..7)
    // -> 8 contiguous fp32 in W's row-major [64][128] storage.
    ABFrag wf[4][4]; // [coltile c][kstep s]
    #pragma unroll
    for (int c = 0; c < 4; ++c) {
        #pragma unroll
        for (int s = 0; s < 4; ++s) {
            const float* wp = W + (16*c + l16)*BEAT_LEN + 32*s + 8*lg;
            f32x4 w0 = *(const f32x4*)(wp);
            f32x4 w1 = *(const f32x4*)(wp + 4);
            wf[c][s].u[0] = pkbf16(w0[0], w0[1]);
            wf[c][s].u[1] = pkbf16(w0[2], w0[3]);
            wf[c][s].u[2] = pkbf16(w1[0], w1[1]);
            wf[c][s].u[3] = pkbf16(w1[2], w1[3]);
        }
    }
    float bv[4];
    #pragma unroll
    for (int c = 0; c < 4; ++c) bv[c] = b[16*c + l16];

    const int gwave = blockIdx.x * WPB + wid;

    for (int rg = gwave; rg < RGROUPS; rg += NWAVES) {
        // A fragment: lane holds A[l16][32s + 8*lg + e] -> 8 contiguous floats
        const float* arow = ecg + (size_t)rg * (16 * BEAT_LEN)
                          + (size_t)l16 * BEAT_LEN + 8 * lg;
        f32x4 a0[4], a1[4];
        #pragma unroll
        for (int s = 0; s < 4; ++s) {
            a0[s] = *(const f32x4*)(arow + 32*s);
            a1[s] = *(const f32x4*)(arow + 32*s + 4);
        }

        f32x4 acc[4];
        #pragma unroll
        for (int c = 0; c < 4; ++c) acc[c] = (f32x4){bv[c], bv[c], bv[c], bv[c]};

        #pragma unroll
        for (int s = 0; s < 4; ++s) {
            ABFrag af;
            af.u[0] = pkbf16(a0[s][0], a0[s][1]);
            af.u[1] = pkbf16(a0[s][2], a0[s][3]);
            af.u[2] = pkbf16(a1[s][0], a1[s][1]);
            af.u[3] = pkbf16(a1[s][2], a1[s][3]);
            #pragma unroll
            for (int c = 0; c < 4; ++c)
                acc[c] = __builtin_amdgcn_mfma_f32_16x16x32_bf16(
                             af.v, wf[c][s].v, acc[c], 0, 0, 0);
        }

        // D mapping (verified m89/m91): col = lane&15, row = 4*(lane>>4)+reg
        float* orow = out + (size_t)rg * (16 * TOKEN_DIM);
        #pragma unroll
        for (int c = 0; c < 4; ++c) {
            #pragma unroll
            for (int r = 0; r < 4; ++r) {
                orow[(4*lg + r) * TOKEN_DIM + 16*c + l16] = acc[c][r];
            }
        }
    }

    // beat_intervals [128,128] = 128.0f, appended after X
    const int gtid = blockIdx.x * blockDim.x + threadIdx.x;
    if (gtid < N_BATCH * N_BEATS) {
        out[(size_t)M_ROWS * TOKEN_DIM + gtid] = 128.0f;
    }
}

extern "C" void kernel_launch(void* const* d_in, const int* in_sizes, int n_in,
                              void* d_out, int out_size, void* d_ws, size_t ws_size,
                              hipStream_t stream) {
    const float* ecg = (const float*)d_in[0];
    const float* W   = (const float*)d_in[1];
    const float* b   = (const float*)d_in[2];
    float* out       = (float*)d_out;
    hipLaunchKernelGGL(ECGTokenizer_53420803228140_kernel,
                       dim3(NBLOCKS), dim3(256), 0, stream,
                       ecg, W, b, out);
}